// Round 7
// baseline (496.445 us; speedup 1.0000x reference)
//
#include <hip/hip_runtime.h>
#include <hip/hip_bf16.h>

constexpr int NN = 50000;
constexpr int NE = 1600000;
constexpr int DI = 512;
constexpr int DH = 256;
constexpr int DO = 64;

constexpr int G1_BLOCKS = ((NN + 127) / 128) * (DH / 128);  // 782
constexpr int SC_BLOCKS = 2048;
constexpr int E4_CAP = NE + NN * 16 + 64;   // rows padded to 16-multiples + tail pad

typedef __attribute__((ext_vector_type(8))) short short8;
typedef __attribute__((ext_vector_type(4))) float f32x4;

__device__ inline ushort f2b(float f) {          // fp32 -> bf16 bits, RNE
    uint u = __float_as_uint(f);
    u += 0x7fffu + ((u >> 16) & 1u);
    return (ushort)(u >> 16);
}
__device__ inline float b2f(ushort u) {
    return __uint_as_float((uint)u << 16);
}

// ---------------- hist + pack: counts[row]++, pr = {(row<<16)|col, bf16val<<16} ----------------

__global__ void k_hist(const int* __restrict__ er, const int* __restrict__ ec,
                       const float* __restrict__ ev, int* __restrict__ counts,
                       uint2* __restrict__ pr) {
    int i = blockIdx.x * blockDim.x + threadIdx.x;
    int stride = gridDim.x * blockDim.x;
    const int4* r4 = (const int4*)er;
    const int4* c4 = (const int4*)ec;
    const float4* v4 = (const float4*)ev;
    for (; i < NE / 4; i += stride) {
        int4 r = r4[i];
        int4 c = c4[i];
        float4 v = v4[i];
        uint4 pa = make_uint4(((uint)r.x << 16) | (uint)c.x, (uint)f2b(v.x) << 16,
                              ((uint)r.y << 16) | (uint)c.y, (uint)f2b(v.y) << 16);
        uint4 pb = make_uint4(((uint)r.z << 16) | (uint)c.z, (uint)f2b(v.z) << 16,
                              ((uint)r.w << 16) | (uint)c.w, (uint)f2b(v.w) << 16);
        *(uint4*)&pr[i * 4]     = pa;
        *(uint4*)&pr[i * 4 + 2] = pb;
        atomicAdd(&counts[r.x], 1);
        atomicAdd(&counts[r.y], 1);
        atomicAdd(&counts[r.z], 1);
        atomicAdd(&counts[r.w], 1);
    }
}

// ---------------- scan (rows padded to 16-multiple) + w2b convert ----------------

__global__ __launch_bounds__(1024) void k_scan(const int* __restrict__ counts,
                                               int* __restrict__ rp,
                                               int* __restrict__ cur,
                                               const float* __restrict__ W2,
                                               ushort* __restrict__ w2b) {
    const int C = (NN + 1023) / 1024;   // 49
    int t = threadIdx.x;
    int lo = t * C;
    int hi = min(lo + C, NN);
    int s = 0;
    for (int i = lo; i < hi; ++i) s += (counts[i] + 15) & ~15;
    __shared__ int buf[1024];
    buf[t] = s;
    __syncthreads();
    for (int off = 1; off < 1024; off <<= 1) {
        int v = (t >= off) ? buf[t - off] : 0;
        __syncthreads();
        buf[t] += v;
        __syncthreads();
    }
    int excl = buf[t] - s;
    for (int i = lo; i < hi; ++i) {
        rp[i] = excl;
        cur[i] = excl;
        excl += (counts[i] + 15) & ~15;
    }
    if (t == 1023) rp[NN] = buf[1023];
    for (int i = t; i < DH * DO; i += 1024) w2b[i] = f2b(W2[i]);
}

// ---------------- fat kernel: GEMM1 (MFMA) + XCD-local scatter ----------------

__global__ __launch_bounds__(256) void k_gemm1_scatter(
        const float* __restrict__ X, const float* __restrict__ W,
        const float* __restrict__ B, ushort* __restrict__ H,
        const uint2* __restrict__ pr, int* __restrict__ cur,
        uint* __restrict__ e4) {
    const int bid = blockIdx.x;
    if (bid < G1_BLOCKS) {
        __shared__ ushort Xs[128 * 32];
        __shared__ ushort Ws[128 * 32];
        const int bm = (bid >> 1) * 128;
        const int bn = (bid & 1) * 128;
        const int tid = threadIdx.x;
        const int wid = tid >> 6, lane = tid & 63;
        const int wm = wid >> 1, wn = wid & 1;
        const int lr = lane & 15, lg = lane >> 4;

        f32x4 acc[4][4];
        #pragma unroll
        for (int i = 0; i < 4; ++i)
            #pragma unroll
            for (int j = 0; j < 4; ++j)
                acc[i][j] = (f32x4){0.f, 0.f, 0.f, 0.f};

        for (int kt = 0; kt < DI; kt += 32) {
            #pragma unroll
            for (int c = 0; c < 4; ++c) {
                int id = tid + c * 256;
                int row = id >> 3, kc = id & 7;
                int gr = bm + row;
                float4 v = {0.f, 0.f, 0.f, 0.f};
                if (gr < NN) v = *(const float4*)(X + (size_t)gr * DI + kt + kc * 4);
                ushort4 p = make_ushort4(f2b(v.x), f2b(v.y), f2b(v.z), f2b(v.w));
                *(ushort4*)&Xs[row * 32 + kc * 4] = p;
            }
            #pragma unroll
            for (int c = 0; c < 2; ++c) {
                int id = tid + c * 256;
                int n = id & 127, g = id >> 7;
                short8 p;
                #pragma unroll
                for (int e = 0; e < 8; ++e)
                    p[e] = (short)f2b(W[(size_t)(kt + g * 8 + e) * DH + bn + n]);
                *(short8*)&Ws[n * 32 + g * 8] = p;
            }
            __syncthreads();

            short8 a[4], b[4];
            #pragma unroll
            for (int f = 0; f < 4; ++f) {
                a[f] = *(short8*)&Xs[(wm * 64 + f * 16 + lr) * 32 + lg * 8];
                b[f] = *(short8*)&Ws[(wn * 64 + f * 16 + lr) * 32 + lg * 8];
            }
            #pragma unroll
            for (int i = 0; i < 4; ++i)
                #pragma unroll
                for (int j = 0; j < 4; ++j)
                    acc[i][j] = __builtin_amdgcn_mfma_f32_16x16x32_bf16(a[i], b[j], acc[i][j], 0, 0, 0);
            __syncthreads();
        }

        #pragma unroll
        for (int i = 0; i < 4; ++i) {
            int r0 = bm + wm * 64 + i * 16 + lg * 4;
            #pragma unroll
            for (int j = 0; j < 4; ++j) {
                int col = bn + wn * 64 + j * 16 + lr;
                float bias = B[col];
                #pragma unroll
                for (int e = 0; e < 4; ++e) {
                    int r = r0 + e;
                    if (r < NN) H[(size_t)r * DH + col] = f2b(acc[i][j][e] + bias);
                }
            }
        }
    } else {
        // scatter: rows partitioned by XCD (blockIdx % 8); per-XCD write window
        // (~1.2 MB of e4 + 25 KB of cur) stays L2-resident.
        const int sb = bid - G1_BLOCKS;
        const int g  = bid & 7;
        const int lo = g * (NN / 8), hi = lo + (NN / 8);
        const int tid = threadIdx.x;
        const uint4* p4 = (const uint4*)pr;     // 2 edges per uint4
        const int NP = NE / 2;
        for (int q = (sb >> 3) * 256 + tid; q < NP; q += (SC_BLOCKS / 8) * 256) {
            uint4 t = p4[q];
            uint r0 = t.x >> 16;
            if (r0 >= (uint)lo && r0 < (uint)hi) {
                int p = atomicAdd(&cur[r0], 1);
                e4[p] = (t.x & 0xffffu) | t.y;
            }
            uint r1 = t.z >> 16;
            if (r1 >= (uint)lo && r1 < (uint)hi) {
                int p = atomicAdd(&cur[r1], 1);
                e4[p] = (t.z & 0xffffu) | t.w;
            }
        }
    }
}

// ---------------- fused SpMM1 + ReLU + GEMM2 ----------------
// wave per row; wave = 2 edge-halves x 32 dim-lanes x 8 dims (short8 = 16 B).
// Rows padded to 16-edge multiples with zero entries (col 0, val 0) ->
// branch-free 16-edge batches, 8 gathers in flight, e4 prefetched between
// gather issue and FMA consumption.

__global__ __launch_bounds__(256) void k_srg(const int* __restrict__ rp,
                                             const uint* __restrict__ e4,
                                             const ushort* __restrict__ H,
                                             const ushort* __restrict__ w2b,
                                             const float* __restrict__ B2,
                                             ushort* __restrict__ H2) {
    __shared__ float hs[4][DH];
    const int tid = threadIdx.x;
    const int w = tid >> 6, lane = tid & 63;
    const int r = blockIdx.x * 4 + w;
    const int s = rp[r], e = rp[r + 1];
    const int half = lane >> 5;       // 0: even edges, 1: odd edges
    const int dl = lane & 31;         // dims 8*dl .. 8*dl+7
    const ushort* base = H + dl * 8;
    const uint4* eq = (const uint4*)e4;

    float a[8] = {0.f, 0.f, 0.f, 0.f, 0.f, 0.f, 0.f, 0.f};

    int qi = s >> 2;
    uint4 q0 = eq[qi], q1 = eq[qi + 1], q2 = eq[qi + 2], q3 = eq[qi + 3];
    for (int i = s; i < e; i += 16) {
        uint u[8];
        u[0] = half ? q0.y : q0.x;  u[1] = half ? q0.w : q0.z;
        u[2] = half ? q1.y : q1.x;  u[3] = half ? q1.w : q1.z;
        u[4] = half ? q2.y : q2.x;  u[5] = half ? q2.w : q2.z;
        u[6] = half ? q3.y : q3.x;  u[7] = half ? q3.w : q3.z;
        short8 h[8];
        #pragma unroll
        for (int k = 0; k < 8; ++k)
            h[k] = *(const short8*)(base + (size_t)(u[k] & 0xffffu) * DH);
        qi += 4;                     // prefetch next batch (pad covers overrun)
        q0 = eq[qi]; q1 = eq[qi + 1]; q2 = eq[qi + 2]; q3 = eq[qi + 3];
        #pragma unroll
        for (int k = 0; k < 8; ++k) {
            float v = __uint_as_float(u[k] & 0xffff0000u);
            #pragma unroll
            for (int d = 0; d < 8; ++d) a[d] += v * b2f((ushort)h[k][d]);
        }
    }
    #pragma unroll
    for (int d = 0; d < 8; ++d) a[d] += __shfl_xor(a[d], 32);
    if (half == 0) {
        *(float4*)&hs[w][dl * 8]     = make_float4(fmaxf(a[0], 0.f), fmaxf(a[1], 0.f),
                                                   fmaxf(a[2], 0.f), fmaxf(a[3], 0.f));
        *(float4*)&hs[w][dl * 8 + 4] = make_float4(fmaxf(a[4], 0.f), fmaxf(a[5], 0.f),
                                                   fmaxf(a[6], 0.f), fmaxf(a[7], 0.f));
    }
    __syncthreads();

    const int rr = tid >> 6;
    const int j  = tid & 63;
    float acc = B2[j];
    #pragma unroll 8
    for (int k = 0; k < DH; ++k) acc += hs[rr][k] * b2f(w2b[k * DO + j]);
    H2[(size_t)(blockIdx.x * 4 + rr) * DO + j] = f2b(acc);
}

// ---------------- SpMM2: out = A @ h2 ----------------
// wave = 8 edge slots x 8 dim-lanes; uint2 e4 loads (2 edges per slot),
// 2 gathers of 16 B in flight per lane; padded rows -> no remainder.

__global__ __launch_bounds__(256) void k_spmm_out(const int* __restrict__ rp,
                                                  const uint* __restrict__ e4,
                                                  const ushort* __restrict__ H2,
                                                  float* __restrict__ OUT) {
    const int r = blockIdx.x * 4 + (threadIdx.x >> 6);
    const int lane = threadIdx.x & 63;
    const int slot = lane >> 3;       // 0..7: edges i+2*slot, i+2*slot+1
    const int dq = lane & 7;          // dims 8*dq .. 8*dq+7
    const int s = rp[r], e = rp[r + 1];
    const ushort* base = H2 + dq * 8;
    float a[8] = {0.f, 0.f, 0.f, 0.f, 0.f, 0.f, 0.f, 0.f};

    for (int i = s; i < e; i += 16) {
        uint2 u = *(const uint2*)(e4 + i + 2 * slot);
        short8 h0 = *(const short8*)(base + (size_t)(u.x & 0xffffu) * DO);
        short8 h1 = *(const short8*)(base + (size_t)(u.y & 0xffffu) * DO);
        float v0 = __uint_as_float(u.x & 0xffff0000u);
        float v1 = __uint_as_float(u.y & 0xffff0000u);
        #pragma unroll
        for (int d = 0; d < 8; ++d)
            a[d] += v0 * b2f((ushort)h0[d]) + v1 * b2f((ushort)h1[d]);
    }
    #pragma unroll
    for (int d = 0; d < 8; ++d) {
        a[d] += __shfl_xor(a[d], 8);
        a[d] += __shfl_xor(a[d], 16);
        a[d] += __shfl_xor(a[d], 32);
    }
    if (slot == 0) {
        float* o = OUT + (size_t)r * DO + dq * 8;
        *(float4*)o       = make_float4(a[0], a[1], a[2], a[3]);
        *(float4*)(o + 4) = make_float4(a[4], a[5], a[6], a[7]);
    }
}

// ---------------- launch ----------------

extern "C" void kernel_launch(void* const* d_in, const int* in_sizes, int n_in,
                              void* d_out, int out_size, void* d_ws, size_t ws_size,
                              hipStream_t stream) {
    const float* x  = (const float*)d_in[0];
    const int*   er = (const int*)d_in[1];
    const int*   ec = (const int*)d_in[2];
    const float* ev = (const float*)d_in[3];
    const float* W1 = (const float*)d_in[4];
    const float* b1 = (const float*)d_in[5];
    const float* W2 = (const float*)d_in[6];
    const float* b2 = (const float*)d_in[7];
    float* out = (float*)d_out;

    char* ws = (char*)d_ws;
    ushort* h1  = (ushort*)ws; ws += (size_t)NN * DH * 2;                    // 25.6 MB
    ushort* h2  = (ushort*)ws; ws += (size_t)NN * DO * 2;                    //  6.4 MB
    uint*  e4   = (uint*)ws;   ws += ((size_t)E4_CAP * 4 + 255) & ~(size_t)255;  // 9.6 MB
    uint2* pr   = (uint2*)ws;  ws += (size_t)NE * 8;                         // 12.8 MB
    int* counts = (int*)ws;    ws += ((size_t)NN * 4 + 255) & ~(size_t)255;
    int* rp     = (int*)ws;    ws += ((size_t)(NN + 1) * 4 + 255) & ~(size_t)255;
    int* cur    = (int*)ws;    ws += ((size_t)NN * 4 + 255) & ~(size_t)255;
    ushort* w2b = (ushort*)ws; ws += ((size_t)DH * DO * 2 + 255) & ~(size_t)255;

    hipMemsetAsync(counts, 0, (size_t)NN * 4, stream);
    hipMemsetAsync(e4, 0, (size_t)E4_CAP * 4, stream);
    k_hist<<<1024, 256, 0, stream>>>(er, ec, ev, counts, pr);
    k_scan<<<1, 1024, 0, stream>>>(counts, rp, cur, W2, w2b);
    k_gemm1_scatter<<<G1_BLOCKS + SC_BLOCKS, 256, 0, stream>>>(
        x, W1, b1, h1, pr, cur, e4);
    k_srg<<<NN / 4, 256, 0, stream>>>(rp, e4, h1, w2b, b2, h2);
    k_spmm_out<<<NN / 4, 256, 0, stream>>>(rp, e4, h2, out);
}

// Round 8
// 495.981 us; speedup vs baseline: 1.0009x; 1.0009x over previous
//
#include <hip/hip_runtime.h>
#include <hip/hip_bf16.h>

constexpr int NN = 50000;
constexpr int NE = 1600000;
constexpr int DI = 512;
constexpr int DH = 256;
constexpr int DO = 64;

constexpr int G1_BLOCKS = ((NN + 127) / 128) * (DH / 128);  // 782
constexpr int H_BLOCKS  = 1024;
constexpr int SC_BLOCKS = 2048;
constexpr int E4_CAP = NE + NN * 16 + 64;   // rows padded to 16-multiples + tail pad

typedef __attribute__((ext_vector_type(8))) short short8;
typedef __attribute__((ext_vector_type(4))) float f32x4;

__device__ inline ushort f2b(float f) {          // fp32 -> bf16 bits, RNE
    uint u = __float_as_uint(f);
    u += 0x7fffu + ((u >> 16) & 1u);
    return (ushort)(u >> 16);
}
__device__ inline float b2f(ushort u) {
    return __uint_as_float((uint)u << 16);
}

// ---------------- fat kernel: GEMM1 (MFMA) + hist/rank/pack ----------------
// hist captures the atomic's return value as the edge's rank within its row:
// pr = {(row<<16)|col, (bf16val<<16)|rank}. Scatter then needs NO atomics.

__global__ __launch_bounds__(256) void k_gemm1_hist(
        const float* __restrict__ X, const float* __restrict__ W,
        const float* __restrict__ B, ushort* __restrict__ H,
        const int* __restrict__ er, const int* __restrict__ ec,
        const float* __restrict__ ev, int* __restrict__ counts,
        uint2* __restrict__ pr) {
    const int bid = blockIdx.x;
    if (bid < G1_BLOCKS) {
        __shared__ ushort Xs[128 * 32];
        __shared__ ushort Ws[128 * 32];
        const int bm = (bid >> 1) * 128;
        const int bn = (bid & 1) * 128;
        const int tid = threadIdx.x;
        const int wid = tid >> 6, lane = tid & 63;
        const int wm = wid >> 1, wn = wid & 1;
        const int lr = lane & 15, lg = lane >> 4;

        f32x4 acc[4][4];
        #pragma unroll
        for (int i = 0; i < 4; ++i)
            #pragma unroll
            for (int j = 0; j < 4; ++j)
                acc[i][j] = (f32x4){0.f, 0.f, 0.f, 0.f};

        for (int kt = 0; kt < DI; kt += 32) {
            #pragma unroll
            for (int c = 0; c < 4; ++c) {
                int id = tid + c * 256;
                int row = id >> 3, kc = id & 7;
                int gr = bm + row;
                float4 v = {0.f, 0.f, 0.f, 0.f};
                if (gr < NN) v = *(const float4*)(X + (size_t)gr * DI + kt + kc * 4);
                ushort4 p = make_ushort4(f2b(v.x), f2b(v.y), f2b(v.z), f2b(v.w));
                *(ushort4*)&Xs[row * 32 + kc * 4] = p;
            }
            #pragma unroll
            for (int c = 0; c < 2; ++c) {
                int id = tid + c * 256;
                int n = id & 127, g = id >> 7;
                short8 p;
                #pragma unroll
                for (int e = 0; e < 8; ++e)
                    p[e] = (short)f2b(W[(size_t)(kt + g * 8 + e) * DH + bn + n]);
                *(short8*)&Ws[n * 32 + g * 8] = p;
            }
            __syncthreads();

            short8 a[4], b[4];
            #pragma unroll
            for (int f = 0; f < 4; ++f) {
                a[f] = *(short8*)&Xs[(wm * 64 + f * 16 + lr) * 32 + lg * 8];
                b[f] = *(short8*)&Ws[(wn * 64 + f * 16 + lr) * 32 + lg * 8];
            }
            #pragma unroll
            for (int i = 0; i < 4; ++i)
                #pragma unroll
                for (int j = 0; j < 4; ++j)
                    acc[i][j] = __builtin_amdgcn_mfma_f32_16x16x32_bf16(a[i], b[j], acc[i][j], 0, 0, 0);
            __syncthreads();
        }

        #pragma unroll
        for (int i = 0; i < 4; ++i) {
            int r0 = bm + wm * 64 + i * 16 + lg * 4;
            #pragma unroll
            for (int j = 0; j < 4; ++j) {
                int col = bn + wn * 64 + j * 16 + lr;
                float bias = B[col];
                #pragma unroll
                for (int e = 0; e < 4; ++e) {
                    int r = r0 + e;
                    if (r < NN) H[(size_t)r * DH + col] = f2b(acc[i][j][e] + bias);
                }
            }
        }
    } else {
        const int hb = bid - G1_BLOCKS;
        const int4* r4 = (const int4*)er;
        const int4* c4 = (const int4*)ec;
        const float4* v4 = (const float4*)ev;
        for (int i = hb * 256 + (int)threadIdx.x; i < NE / 4; i += H_BLOCKS * 256) {
            int4 r = r4[i];
            int4 c = c4[i];
            float4 v = v4[i];
            uint k0 = (uint)atomicAdd(&counts[r.x], 1);
            uint k1 = (uint)atomicAdd(&counts[r.y], 1);
            uint k2 = (uint)atomicAdd(&counts[r.z], 1);
            uint k3 = (uint)atomicAdd(&counts[r.w], 1);
            uint4 pa = make_uint4(((uint)r.x << 16) | (uint)c.x, ((uint)f2b(v.x) << 16) | k0,
                                  ((uint)r.y << 16) | (uint)c.y, ((uint)f2b(v.y) << 16) | k1);
            uint4 pb = make_uint4(((uint)r.z << 16) | (uint)c.z, ((uint)f2b(v.z) << 16) | k2,
                                  ((uint)r.w << 16) | (uint)c.w, ((uint)f2b(v.w) << 16) | k3);
            *(uint4*)&pr[i * 4]     = pa;
            *(uint4*)&pr[i * 4 + 2] = pb;
        }
    }
}

// ---------------- scan (rows padded to 16-multiple) + w2b convert ----------------

__global__ __launch_bounds__(1024) void k_scan(const int* __restrict__ counts,
                                               int* __restrict__ rp,
                                               const float* __restrict__ W2,
                                               ushort* __restrict__ w2b) {
    const int C = (NN + 1023) / 1024;   // 49
    int t = threadIdx.x;
    int lo = t * C;
    int hi = min(lo + C, NN);
    int s = 0;
    for (int i = lo; i < hi; ++i) s += (counts[i] + 15) & ~15;
    __shared__ int buf[1024];
    buf[t] = s;
    __syncthreads();
    for (int off = 1; off < 1024; off <<= 1) {
        int v = (t >= off) ? buf[t - off] : 0;
        __syncthreads();
        buf[t] += v;
        __syncthreads();
    }
    int excl = buf[t] - s;
    for (int i = lo; i < hi; ++i) {
        rp[i] = excl;
        excl += (counts[i] + 15) & ~15;
    }
    if (t == 1023) rp[NN] = buf[1023];
    for (int i = t; i < DH * DO; i += 1024) w2b[i] = f2b(W2[i]);
}

// ---------------- scatter: atomic-free (slot = rp[row] + rank) ----------------
// rows partitioned by XCD (blockIdx % 8); per-XCD write window ~1.2 MB of e4
// stays L2-resident -> full-line writebacks.

__global__ __launch_bounds__(256) void k_scatter(const uint2* __restrict__ pr,
                                                 const int* __restrict__ rp,
                                                 uint* __restrict__ e4) {
    const int g = blockIdx.x & 7;
    const uint lo = g * (NN / 8), hi = lo + (NN / 8);
    const uint4* p4 = (const uint4*)pr;     // 2 edges per uint4
    const int NP = NE / 2;
    for (int q = (blockIdx.x >> 3) * 256 + (int)threadIdx.x; q < NP;
         q += (SC_BLOCKS / 8) * 256) {
        uint4 t = p4[q];
        uint r0 = t.x >> 16;
        if (r0 >= lo && r0 < hi)
            e4[rp[r0] + (t.y & 0xffffu)] = (t.x & 0xffffu) | (t.y & 0xffff0000u);
        uint r1 = t.z >> 16;
        if (r1 >= lo && r1 < hi)
            e4[rp[r1] + (t.w & 0xffffu)] = (t.z & 0xffffu) | (t.w & 0xffff0000u);
    }
}

// ---------------- fused SpMM1 + ReLU + GEMM2 (unchanged from r7) ----------------

__global__ __launch_bounds__(256) void k_srg(const int* __restrict__ rp,
                                             const uint* __restrict__ e4,
                                             const ushort* __restrict__ H,
                                             const ushort* __restrict__ w2b,
                                             const float* __restrict__ B2,
                                             ushort* __restrict__ H2) {
    __shared__ float hs[4][DH];
    const int tid = threadIdx.x;
    const int w = tid >> 6, lane = tid & 63;
    const int r = blockIdx.x * 4 + w;
    const int s = rp[r], e = rp[r + 1];
    const int half = lane >> 5;
    const int dl = lane & 31;
    const ushort* base = H + dl * 8;
    const uint4* eq = (const uint4*)e4;

    float a[8] = {0.f, 0.f, 0.f, 0.f, 0.f, 0.f, 0.f, 0.f};

    int qi = s >> 2;
    uint4 q0 = eq[qi], q1 = eq[qi + 1], q2 = eq[qi + 2], q3 = eq[qi + 3];
    for (int i = s; i < e; i += 16) {
        uint u[8];
        u[0] = half ? q0.y : q0.x;  u[1] = half ? q0.w : q0.z;
        u[2] = half ? q1.y : q1.x;  u[3] = half ? q1.w : q1.z;
        u[4] = half ? q2.y : q2.x;  u[5] = half ? q2.w : q2.z;
        u[6] = half ? q3.y : q3.x;  u[7] = half ? q3.w : q3.z;
        short8 h[8];
        #pragma unroll
        for (int k = 0; k < 8; ++k)
            h[k] = *(const short8*)(base + (size_t)(u[k] & 0xffffu) * DH);
        qi += 4;
        q0 = eq[qi]; q1 = eq[qi + 1]; q2 = eq[qi + 2]; q3 = eq[qi + 3];
        #pragma unroll
        for (int k = 0; k < 8; ++k) {
            float v = __uint_as_float(u[k] & 0xffff0000u);
            #pragma unroll
            for (int d = 0; d < 8; ++d) a[d] += v * b2f((ushort)h[k][d]);
        }
    }
    #pragma unroll
    for (int d = 0; d < 8; ++d) a[d] += __shfl_xor(a[d], 32);
    if (half == 0) {
        *(float4*)&hs[w][dl * 8]     = make_float4(fmaxf(a[0], 0.f), fmaxf(a[1], 0.f),
                                                   fmaxf(a[2], 0.f), fmaxf(a[3], 0.f));
        *(float4*)&hs[w][dl * 8 + 4] = make_float4(fmaxf(a[4], 0.f), fmaxf(a[5], 0.f),
                                                   fmaxf(a[6], 0.f), fmaxf(a[7], 0.f));
    }
    __syncthreads();

    const int rr = tid >> 6;
    const int j  = tid & 63;
    float acc = B2[j];
    #pragma unroll 8
    for (int k = 0; k < DH; ++k) acc += hs[rr][k] * b2f(w2b[k * DO + j]);
    H2[(size_t)(blockIdx.x * 4 + rr) * DO + j] = f2b(acc);
}

// ---------------- SpMM2: out = A @ h2, dim-segmented for L2 pinning ----------------
// seg = bid&3 (16 dims, 32 B/col): seg s lives on XCDs {s, s+4}; per-XCD h2
// hot set = 50000*32 B = 1.6 MB < 4 MB L2. Each 64 B OUT line has one writer.
// wave = 16 edge slots x 4 dim-lanes (ushort4); rows padded to 16 -> no tail.

__global__ __launch_bounds__(256) void k_spmm_out(const int* __restrict__ rp,
                                                  const uint* __restrict__ e4,
                                                  const ushort* __restrict__ H2,
                                                  float* __restrict__ OUT) {
    const int seg = blockIdx.x & 3;
    const int r = (blockIdx.x >> 2) * 4 + (threadIdx.x >> 6);
    const int lane = threadIdx.x & 63;
    const int slot = lane >> 2;       // 0..15
    const int dq = lane & 3;          // dims seg*16 + dq*4 ..+3
    const int s = rp[r], e = rp[r + 1];
    const ushort* base = H2 + seg * 16 + dq * 4;
    float a0 = 0.f, a1 = 0.f, a2 = 0.f, a3 = 0.f;

    for (int i = s + slot; i < e; i += 16) {
        uint u = e4[i];
        ushort4 h = *(const ushort4*)(base + (size_t)(u & 0xffffu) * DO);
        float v = __uint_as_float(u & 0xffff0000u);
        a0 += v * b2f(h.x); a1 += v * b2f(h.y); a2 += v * b2f(h.z); a3 += v * b2f(h.w);
    }
    #pragma unroll
    for (int m = 4; m < 64; m <<= 1) {
        a0 += __shfl_xor(a0, m); a1 += __shfl_xor(a1, m);
        a2 += __shfl_xor(a2, m); a3 += __shfl_xor(a3, m);
    }
    if (slot == 0) {
        *(float4*)(OUT + (size_t)r * DO + seg * 16 + dq * 4) = make_float4(a0, a1, a2, a3);
    }
}

// ---------------- launch ----------------

extern "C" void kernel_launch(void* const* d_in, const int* in_sizes, int n_in,
                              void* d_out, int out_size, void* d_ws, size_t ws_size,
                              hipStream_t stream) {
    const float* x  = (const float*)d_in[0];
    const int*   er = (const int*)d_in[1];
    const int*   ec = (const int*)d_in[2];
    const float* ev = (const float*)d_in[3];
    const float* W1 = (const float*)d_in[4];
    const float* b1 = (const float*)d_in[5];
    const float* W2 = (const float*)d_in[6];
    const float* b2 = (const float*)d_in[7];
    float* out = (float*)d_out;

    char* ws = (char*)d_ws;
    ushort* h1  = (ushort*)ws; ws += (size_t)NN * DH * 2;                    // 25.6 MB
    ushort* h2  = (ushort*)ws; ws += (size_t)NN * DO * 2;                    //  6.4 MB
    uint*  e4   = (uint*)ws;   ws += ((size_t)E4_CAP * 4 + 255) & ~(size_t)255;  // 9.6 MB
    uint2* pr   = (uint2*)ws;  ws += (size_t)NE * 8;                         // 12.8 MB
    int* counts = (int*)ws;    ws += ((size_t)NN * 4 + 255) & ~(size_t)255;
    int* rp     = (int*)ws;    ws += ((size_t)(NN + 1) * 4 + 255) & ~(size_t)255;
    ushort* w2b = (ushort*)ws; ws += ((size_t)DH * DO * 2 + 255) & ~(size_t)255;

    hipMemsetAsync(counts, 0, (size_t)NN * 4, stream);
    hipMemsetAsync(e4, 0, (size_t)E4_CAP * 4, stream);
    k_gemm1_hist<<<G1_BLOCKS + H_BLOCKS, 256, 0, stream>>>(
        x, W1, b1, h1, er, ec, ev, counts, pr);
    k_scan<<<1, 1024, 0, stream>>>(counts, rp, W2, w2b);
    k_scatter<<<SC_BLOCKS, 256, 0, stream>>>(pr, rp, e4);
    k_srg<<<NN / 4, 256, 0, stream>>>(rp, e4, h1, w2b, b2, h2);
    k_spmm_out<<<(NN / 4) * 4, 256, 0, stream>>>(rp, e4, h2, out);
}